// Round 1
// baseline (3800.642 us; speedup 1.0000x reference)
//
#include <hip/hip_runtime.h>
#include <cstdint>
#include <cstddef>

// Problem constants (reference: T,B,H_IN,H_HID = 2048,64,256,256)
#define T_LEN 2048
#define B_N   64
#define H_INP 256
#define H_HID 256
#define G3    768              // 3*H_HID (gates r,z,n)
#define M_ROWS (T_LEN * B_N)   // 131072
#define SCH   8                // scan steps per LDS chunk

typedef _Float16 f16;
typedef _Float16 f16x2 __attribute__((ext_vector_type(2)));
typedef _Float16 f16x8 __attribute__((ext_vector_type(8)));
typedef float    f32x4 __attribute__((ext_vector_type(4)));

// ---- async global->LDS, 16 B per lane; ldsbase must be wave-uniform ----
static __device__ __forceinline__ void gldl16(const void* g, void* ldsbase, void* ldsexact) {
#if __has_builtin(__builtin_amdgcn_global_load_lds)
  __builtin_amdgcn_global_load_lds((const __attribute__((address_space(1))) void*)g,
                                   (__attribute__((address_space(3))) void*)ldsbase, 16, 0, 0);
  (void)ldsexact;
#else
  *(uint4*)ldsexact = *(const uint4*)g;
#endif
}

// ---------------------------------------------------------------- zero d_out
__global__ void k_zero(float4* __restrict__ p, int n4) {
  int i = blockIdx.x * blockDim.x + threadIdx.x;
  int stride = gridDim.x * blockDim.x;
  float4 z; z.x = z.y = z.z = z.w = 0.f;
  for (; i < n4; i += stride) p[i] = z;
}

// ------------------------------------------------------------- f32 -> f16
__global__ void k_cvt(const float2* __restrict__ s, f16x2* __restrict__ d, int n2) {
  int i = blockIdx.x * blockDim.x + threadIdx.x;
  int stride = gridDim.x * blockDim.x;
  for (; i < n2; i += stride) {
    float2 v = s[i];
    f16x2 p; p.x = (f16)v.x; p.y = (f16)v.y;
    d[i] = p;
  }
}

// ---------------------------------------------- per-column pack: tidx, lens
__global__ __launch_bounds__(64) void k_prep_col(const int* __restrict__ mask,
                                                 unsigned short* __restrict__ tidx,
                                                 int* __restrict__ lens) {
  const int b = blockIdx.x;
  const int lane = threadIdx.x;
  unsigned short* tp = tidx + b * T_LEN;
  int base = 0;
  for (int c = 0; c < T_LEN / 64; ++c) {
    int t = c * 64 + lane;
    bool m = mask[t * B_N + b] != 0;
    unsigned long long bal = __ballot(m);
    int pc = __popcll(bal & ((1ull << lane) - 1ull));
    if (m) tp[base + pc] = (unsigned short)t;
    base += __popcll(bal);
  }
  if (lane == 0) lens[b] = base;
}

// --------------------------------------------------- per-row true counts
__global__ __launch_bounds__(256) void k_rowcnt(const int* __restrict__ mask,
                                                int* __restrict__ rowcnt) {
  int g = blockIdx.x * 256 + threadIdx.x;
  int t = g >> 6, lane = g & 63;
  bool m = mask[t * B_N + lane] != 0;
  unsigned long long bal = __ballot(m);
  if (lane == 0) rowcnt[t] = __popcll(bal);
}

// ------------------------------------------- exclusive prefix of rowcnt[2048]
__global__ __launch_bounds__(512) void k_rowpref(const int* __restrict__ rowcnt,
                                                 int* __restrict__ rowpref,
                                                 int* __restrict__ ntru) {
  const int tid = threadIdx.x;
  const int lane = tid & 63, w = tid >> 6;
  int4 v = ((const int4*)rowcnt)[tid];
  int s = v.x + v.y + v.z + v.w;
  int incl = s;
  for (int d = 1; d < 64; d <<= 1) {
    int t = __shfl_up(incl, d, 64);
    if (lane >= d) incl += t;
  }
  __shared__ int wt[8], wo[8];
  if (lane == 63) wt[w] = incl;
  __syncthreads();
  if (tid == 0) {
    int run = 0;
    for (int i = 0; i < 8; ++i) { wo[i] = run; run += wt[i]; }
    ntru[0] = run;
  }
  __syncthreads();
  int base = wo[w] + incl - s;
  int4 o; o.x = base; o.y = base + v.x; o.z = o.y + v.y; o.w = o.z + v.z;
  ((int4*)rowpref)[tid] = o;
}

// --------------------------------------------------- inverse permutation
__global__ __launch_bounds__(256) void k_inv(const int* __restrict__ mask,
                                             const int* __restrict__ rowpref,
                                             int* __restrict__ inv) {
  int g = blockIdx.x * 256 + threadIdx.x;
  int t = g >> 6, lane = g & 63;
  bool m = mask[t * B_N + lane] != 0;
  unsigned long long bal = __ballot(m);
  int r = rowpref[t] + __popcll(bal & ((1ull << lane) - 1ull));
  if (m) inv[r] = t * B_N + lane;
}

// ---------------------------- invT[b][k] = (k*64+b < Nt) ? inv[k*64+b] : -1
__global__ __launch_bounds__(256) void k_invT(const int* __restrict__ inv,
                                              const int* __restrict__ ntru,
                                              int* __restrict__ invT) {
  int j = blockIdx.x * 256 + threadIdx.x;   // j = k*B + b
  int v = (j < ntru[0]) ? inv[j] : -1;
  invT[(j & 63) * T_LEN + (j >> 6)] = v;
}

// ------------------------------------------- gi = X @ W_ih^T + b_ih (f16 MFMA)
__global__ __launch_bounds__(256) void k_gemm(const f16* __restrict__ X,
                                              const f16* __restrict__ W,
                                              const float* __restrict__ bias,
                                              f16* __restrict__ GI) {
  const int lane = threadIdx.x & 63;
  const int wave = threadIdx.x >> 6;
  const int m0 = blockIdx.x * 64 + wave * 16;
  const int n0 = blockIdx.y * 64;
  const int idx16 = lane & 15;
  const int kofs  = (lane >> 4) * 8;

  __shared__ __align__(16) f16 st[4][16][72];

  const f16* ap  = X + (size_t)(m0 + idx16) * H_INP + kofs;
  const f16* bp0 = W + (size_t)(n0 + idx16) * H_INP + kofs;

  f32x4 acc[4] = { {0,0,0,0}, {0,0,0,0}, {0,0,0,0}, {0,0,0,0} };
#pragma unroll
  for (int kt = 0; kt < 8; ++kt) {
    f16x8 a = *(const f16x8*)(ap + kt * 32);
#pragma unroll
    for (int nt = 0; nt < 4; ++nt) {
      f16x8 bb = *(const f16x8*)(bp0 + (size_t)nt * 16 * H_INP + kt * 32);
      acc[nt] = __builtin_amdgcn_mfma_f32_16x16x32_f16(a, bb, acc[nt], 0, 0, 0);
    }
  }
  // C/D layout: row = (lane>>4)*4 + r, col = lane&15
#pragma unroll
  for (int nt = 0; nt < 4; ++nt) {
    const int col = nt * 16 + idx16;
    const float bv = bias[n0 + col];
#pragma unroll
    for (int r = 0; r < 4; ++r)
      st[wave][(lane >> 4) * 4 + r][col] = (f16)(acc[nt][r] + bv);
  }
  // same-wave LDS RAW (compiler inserts lgkmcnt wait); no barrier needed
  {
    const int row = lane >> 2, seg = lane & 3;
    const uint4* sp = (const uint4*)&st[wave][row][seg * 16];
    uint4 v0 = sp[0], v1 = sp[1];
    uint4* gp = (uint4*)(GI + (size_t)(m0 + row) * G3 + n0 + seg * 16);
    gp[0] = v0; gp[1] = v1;
  }
}

// -------------------------------------------------- GRU scan, 1 column / block
// MFMA rewrite: the h @ Whh^T matvec moves from the VALU pipe (192 fdot2 +
// DPP butterflies per thread, ~2000 issue-cyc/step at 2 waves/SIMD) to the
// matrix pipe: 48 n-tiles x 8 k-tiles of mfma_f32_16x16x32_f16 with the
// h-vector replicated into all 16 B-columns (C columns identical -> no
// cross-lane reduction at all). 4 waves, 1 wave/SIMD, 512-VGPR budget:
// weights = 384 VGPR/lane (wave w owns n-tiles w+4i, i=0..11).
// Tile->wave assignment mod 4 means gate j's (r,z,n) rows (j, j+256, j+512)
// all come from the SAME wave -> ghs needs only intra-wave lgkmcnt ordering,
// no barrier. hf16 and outb are double-buffered -> ONE __syncthreads/step.
__global__ __launch_bounds__(256)
__attribute__((amdgpu_waves_per_eu(1, 1)))
void k_scan(const f16* __restrict__ Whh,
            const f16* __restrict__ GI,
            const float* __restrict__ h0,
            const float* __restrict__ bhh,
            const unsigned short* __restrict__ tidx,
            const int* __restrict__ lens,
            const int* __restrict__ invT,
            float* __restrict__ out) {
  const int b = blockIdx.x;
  const int tid = threadIdx.x;
  const int w = tid >> 6;          // wave 0..3
  const int lane = tid & 63;
  const int g = lane >> 4;         // k-group / C-row group, 0..3
  const int c = lane & 15;         // replicated column

  __shared__ __align__(16) f16   GIbuf[2][SCH * G3];    // 24576 B
  __shared__ __align__(16) float outb[2][SCH * H_HID];  // 16384 B
  __shared__ __align__(16) float ghs[G3];               //  3072 B
  __shared__ __align__(16) f16   hf[2][H_HID];          //  1024 B
  __shared__ unsigned short tcol[T_LEN];                //  4096 B
  __shared__ int      invcol[T_LEN];                    //  8192 B

  const int L = lens[b];

  // ---- weights: wave w owns n-tiles t = w+4i (i=0..11), 8 k-tiles each ----
  // A-frag layout (16x16x32): lane holds A[row = c][k = g*8 + e], e=0..7
  f16x8 wA[96];
#pragma unroll
  for (int i = 0; i < 12; ++i) {
    const f16* wp = Whh + (size_t)((w + 4 * i) * 16 + c) * H_HID + g * 8;
#pragma unroll
    for (int kt = 0; kt < 8; ++kt)
      wA[i * 8 + kt] = *(const f16x8*)(wp + kt * 32);
  }

  // gate element owned by this thread: tiles == w (mod 4) -> all 3 gh rows
  // (j, j+256, j+512) are produced by this wave's own MFMAs.
  const int j = (w + 4 * g) * 16 + c;
  const float bh0 = bhh[j];
  const float bh1 = bhh[H_HID + j];
  const float bh2 = bhh[2 * H_HID + j];

  // ---- stage per-column metadata + h0 ----
  for (int i = tid; i < T_LEN; i += 256) {
    tcol[i] = tidx[b * T_LEN + i];
    invcol[i] = invT[b * T_LEN + i];
  }
  float h_reg = h0[b * H_HID + j];
  hf[0][j] = (f16)h_reg;
  __syncthreads();   // tcol/invcol/hf[0] ready

  const char* GIc = (const char*)GI;
  const int wavbase = w << 10;

  // issue async prefetch of chunk m into GIbuf[m&1] (16 B/lane DMA, 3 rounds)
  auto issue_chunk = [&](int m) {
#pragma unroll
    for (int rnd = 0; rnd < 3; ++rnd) {
      int p = rnd * 4096 + tid * 16;          // bytes [0, 12288)
      int r = p / 1536;
      int kk = m * SCH + r;
      int t = tcol[kk < L ? kk : 0] & (T_LEN - 1);
      const char* src = GIc + ((size_t)((t << 6) + b)) * 1536 + (p - r * 1536);
      char* dbase = (char*)GIbuf[m & 1] + rnd * 4096 + wavbase;
      gldl16(src, dbase, (char*)GIbuf[m & 1] + p);
    }
  };

  issue_chunk(0);
  __syncthreads();   // vmcnt(0) drain before barrier -> chunk 0 landed

  const f32x4 z4 = {0.f, 0.f, 0.f, 0.f};

  const int nchunks = (L + SCH - 1) >> 3;
  for (int n = 0; n < nchunks; ++n) {
    const int par = n & 1;
    if (n + 1 < nchunks) issue_chunk(n + 1);   // lands during this chunk
    // flush chunk n-1 output rows from outb[par^1] (no race: other buffer)
    if (n > 0) {
      int r = tid >> 5, c8 = (tid & 31) << 3;
      int kk = (n - 1) * SCH + r;
      if (kk < L) {
        int iv = invcol[kk];
        if (iv >= 0) {
          const float* sb = &outb[par ^ 1][r * H_HID + c8];
          float* gp = out + (size_t)iv * H_HID + c8;
          *(float4*)gp = *(const float4*)sb;
          *(float4*)(gp + 4) = *(const float4*)(sb + 4);
        }
      }
    }

    const int kbase = n * SCH;
    const int smax = (L - kbase < SCH) ? (L - kbase) : SCH;
    for (int s = 0; s < smax; ++s) {
      const int rd = (kbase + s) & 1;   // hf read buffer this step
      // --- B fragments: h replicated into all 16 cols (broadcast reads) ---
      f16x8 bf[8];
#pragma unroll
      for (int kt = 0; kt < 8; ++kt)
        bf[kt] = *(const f16x8*)(&hf[rd][kt * 32 + g * 8]);
      // --- matvec on MFMA pipe, 6 tiles at a time (acc pressure) ---
#pragma unroll
      for (int half = 0; half < 2; ++half) {
        f32x4 acc[6];
#pragma unroll
        for (int i = 0; i < 6; ++i)
          acc[i] = __builtin_amdgcn_mfma_f32_16x16x32_f16(
              wA[(half * 6 + i) * 8], bf[0], z4, 0, 0, 0);
#pragma unroll
        for (int kt = 1; kt < 8; ++kt)
#pragma unroll
          for (int i = 0; i < 6; ++i)
            acc[i] = __builtin_amdgcn_mfma_f32_16x16x32_f16(
                wA[(half * 6 + i) * 8 + kt], bf[kt], acc[i], 0, 0, 0);
        // C replicated across cols; rows g*4+r. Lane c==0 of each g writes.
        if (c == 0) {
#pragma unroll
          for (int i = 0; i < 6; ++i)
            *(f32x4*)(&ghs[(w + 4 * (half * 6 + i)) * 16 + g * 4]) = acc[i];
        }
      }
      // --- gates: intra-wave LDS RAW on ghs (lgkmcnt), no barrier ---
      {
        const f16* gib = GIbuf[par] + s * G3;
        const float gi0 = (float)gib[j];
        const float gi1 = (float)gib[H_HID + j];
        const float gi2 = (float)gib[2 * H_HID + j];
        const float ghr = ghs[j] + bh0;
        const float ghz = ghs[H_HID + j] + bh1;
        const float ghn = ghs[2 * H_HID + j] + bh2;
        const float rg = __builtin_amdgcn_rcpf(1.f + __expf(-(gi0 + ghr)));
        const float zg = __builtin_amdgcn_rcpf(1.f + __expf(-(gi1 + ghz)));
        const float xx = gi2 + rg * ghn;
        const float ng = 1.f - 2.f * __builtin_amdgcn_rcpf(1.f + __expf(2.f * xx));
        const float hn = (1.f - zg) * ng + zg * h_reg;
        h_reg = hn;
        hf[rd ^ 1][j] = (f16)hn;        // double-buffered: no read/write race
        outb[par][s * H_HID + j] = hn;
      }
      __syncthreads();   // hf[rd^1] complete before next step's bf reads
    }
  }
  // tail flush (last chunk)
  if (L > 0) {
    const int nc = nchunks - 1;
    int r = tid >> 5, c8 = (tid & 31) << 3;
    int kk = nc * SCH + r;
    if (kk < L) {
      int iv = invcol[kk];
      if (iv >= 0) {
        const float* sb = &outb[nc & 1][r * H_HID + c8];
        float* gp = out + (size_t)iv * H_HID + c8;
        *(float4*)gp = *(const float4*)sb;
        *(float4*)(gp + 4) = *(const float4*)(sb + 4);
      }
    }
  }
  out[(size_t)M_ROWS * H_HID + (size_t)b * H_HID + j] = h_reg;
}

// ---------------------------------------------------------------------------
extern "C" void kernel_launch(void* const* d_in, const int* in_sizes, int n_in,
                              void* d_out, int out_size, void* d_ws, size_t ws_size,
                              hipStream_t stream) {
  const float* x    = (const float*)d_in[0];
  const float* h0   = (const float*)d_in[1];
  const int*   mask = (const int*)d_in[2];
  const float* wih  = (const float*)d_in[3];
  const float* whh  = (const float*)d_in[4];
  const float* bih  = (const float*)d_in[5];
  const float* bhh  = (const float*)d_in[6];
  float* out = (float*)d_out;

  // workspace layout (~270.3 MB; invT reuses the X16 region after k_gemm)
  char* ws = (char*)d_ws;
  f16* X16   = (f16*)(ws + 0);                       //  67,108,864 B
  int* invT  = (int*)(ws + 0);                       //     524,288 B (after gemm)
  f16* Wih16 = (f16*)(ws + 67108864);                //     393,216 B
  f16* Whh16 = (f16*)(ws + 67502080);                //     393,216 B
  f16* GI    = (f16*)(ws + 67895296);                // 201,326,592 B
  unsigned short* tidx = (unsigned short*)(ws + 269221888);  // 262,144 B
  int* rowcnt  = (int*)(ws + 269484032);             //       8,192 B
  int* rowpref = (int*)(ws + 269492224);             //       8,192 B
  int* inv   = (int*)(ws + 269746176);               //     524,288 B
  int* lens  = (int*)(ws + 270270464);               //         256 B
  int* ntru  = (int*)(ws + 270270720);               //           4 B

  hipLaunchKernelGGL(k_zero, dim3(4096), dim3(256), 0, stream,
                     (float4*)d_out, out_size / 4);
  hipLaunchKernelGGL(k_cvt, dim3(4096), dim3(256), 0, stream,
                     (const float2*)x, (f16x2*)X16, M_ROWS * H_INP / 2);
  hipLaunchKernelGGL(k_cvt, dim3(96), dim3(256), 0, stream,
                     (const float2*)wih, (f16x2*)Wih16, G3 * H_INP / 2);
  hipLaunchKernelGGL(k_cvt, dim3(96), dim3(256), 0, stream,
                     (const float2*)whh, (f16x2*)Whh16, G3 * H_INP / 2);
  hipLaunchKernelGGL(k_prep_col, dim3(B_N), dim3(64), 0, stream,
                     mask, tidx, lens);
  hipLaunchKernelGGL(k_rowcnt, dim3(512), dim3(256), 0, stream, mask, rowcnt);
  hipLaunchKernelGGL(k_rowpref, dim3(1), dim3(512), 0, stream,
                     rowcnt, rowpref, ntru);
  hipLaunchKernelGGL(k_inv, dim3(512), dim3(256), 0, stream,
                     mask, rowpref, inv);
  hipLaunchKernelGGL(k_gemm, dim3(M_ROWS / 64, G3 / 64), dim3(256), 0, stream,
                     X16, Wih16, bih, GI);
  hipLaunchKernelGGL(k_invT, dim3(512), dim3(256), 0, stream,
                     inv, ntru, invT);
  hipLaunchKernelGGL(k_scan, dim3(B_N), dim3(256), 0, stream,
                     Whh16, GI, h0, bhh, tidx, lens, invT, out);
}

// Round 2
// 3304.399 us; speedup vs baseline: 1.1502x; 1.1502x over previous
//
#include <hip/hip_runtime.h>
#include <cstdint>
#include <cstddef>

// Problem constants (reference: T,B,H_IN,H_HID = 2048,64,256,256)
#define T_LEN 2048
#define B_N   64
#define H_INP 256
#define H_HID 256
#define G3    768              // 3*H_HID (gates r,z,n)
#define M_ROWS (T_LEN * B_N)   // 131072
#define SCH   8                // scan steps per LDS chunk

typedef _Float16 f16;
typedef _Float16 f16x2 __attribute__((ext_vector_type(2)));
typedef _Float16 f16x8 __attribute__((ext_vector_type(8)));
typedef float    f32x4 __attribute__((ext_vector_type(4)));

// ---- async global->LDS, 16 B per lane; ldsbase must be wave-uniform ----
static __device__ __forceinline__ void gldl16(const void* g, void* ldsbase, void* ldsexact) {
#if __has_builtin(__builtin_amdgcn_global_load_lds)
  __builtin_amdgcn_global_load_lds((const __attribute__((address_space(1))) void*)g,
                                   (__attribute__((address_space(3))) void*)ldsbase, 16, 0, 0);
  (void)ldsexact;
#else
  *(uint4*)ldsexact = *(const uint4*)g;
#endif
}

// ---------------------------------------------------------------- zero d_out
__global__ void k_zero(float4* __restrict__ p, int n4) {
  int i = blockIdx.x * blockDim.x + threadIdx.x;
  int stride = gridDim.x * blockDim.x;
  float4 z; z.x = z.y = z.z = z.w = 0.f;
  for (; i < n4; i += stride) p[i] = z;
}

// ------------------------------------------------------------- f32 -> f16
__global__ void k_cvt(const float2* __restrict__ s, f16x2* __restrict__ d, int n2) {
  int i = blockIdx.x * blockDim.x + threadIdx.x;
  int stride = gridDim.x * blockDim.x;
  for (; i < n2; i += stride) {
    float2 v = s[i];
    f16x2 p; p.x = (f16)v.x; p.y = (f16)v.y;
    d[i] = p;
  }
}

// ---------------------------------------------- per-column pack: tidx, lens
__global__ __launch_bounds__(64) void k_prep_col(const int* __restrict__ mask,
                                                 unsigned short* __restrict__ tidx,
                                                 int* __restrict__ lens) {
  const int b = blockIdx.x;
  const int lane = threadIdx.x;
  unsigned short* tp = tidx + b * T_LEN;
  int base = 0;
  for (int c = 0; c < T_LEN / 64; ++c) {
    int t = c * 64 + lane;
    bool m = mask[t * B_N + b] != 0;
    unsigned long long bal = __ballot(m);
    int pc = __popcll(bal & ((1ull << lane) - 1ull));
    if (m) tp[base + pc] = (unsigned short)t;
    base += __popcll(bal);
  }
  if (lane == 0) lens[b] = base;
}

// --------------------------------------------------- per-row true counts
__global__ __launch_bounds__(256) void k_rowcnt(const int* __restrict__ mask,
                                                int* __restrict__ rowcnt) {
  int g = blockIdx.x * 256 + threadIdx.x;
  int t = g >> 6, lane = g & 63;
  bool m = mask[t * B_N + lane] != 0;
  unsigned long long bal = __ballot(m);
  if (lane == 0) rowcnt[t] = __popcll(bal);
}

// ------------------------------------------- exclusive prefix of rowcnt[2048]
__global__ __launch_bounds__(512) void k_rowpref(const int* __restrict__ rowcnt,
                                                 int* __restrict__ rowpref,
                                                 int* __restrict__ ntru) {
  const int tid = threadIdx.x;
  const int lane = tid & 63, w = tid >> 6;
  int4 v = ((const int4*)rowcnt)[tid];
  int s = v.x + v.y + v.z + v.w;
  int incl = s;
  for (int d = 1; d < 64; d <<= 1) {
    int t = __shfl_up(incl, d, 64);
    if (lane >= d) incl += t;
  }
  __shared__ int wt[8], wo[8];
  if (lane == 63) wt[w] = incl;
  __syncthreads();
  if (tid == 0) {
    int run = 0;
    for (int i = 0; i < 8; ++i) { wo[i] = run; run += wt[i]; }
    ntru[0] = run;
  }
  __syncthreads();
  int base = wo[w] + incl - s;
  int4 o; o.x = base; o.y = base + v.x; o.z = o.y + v.y; o.w = o.z + v.z;
  ((int4*)rowpref)[tid] = o;
}

// --------------------------------------------------- inverse permutation
__global__ __launch_bounds__(256) void k_inv(const int* __restrict__ mask,
                                             const int* __restrict__ rowpref,
                                             int* __restrict__ inv) {
  int g = blockIdx.x * 256 + threadIdx.x;
  int t = g >> 6, lane = g & 63;
  bool m = mask[t * B_N + lane] != 0;
  unsigned long long bal = __ballot(m);
  int r = rowpref[t] + __popcll(bal & ((1ull << lane) - 1ull));
  if (m) inv[r] = t * B_N + lane;
}

// ---------------------------- invT[b][k] = (k*64+b < Nt) ? inv[k*64+b] : -1
__global__ __launch_bounds__(256) void k_invT(const int* __restrict__ inv,
                                              const int* __restrict__ ntru,
                                              int* __restrict__ invT) {
  int j = blockIdx.x * 256 + threadIdx.x;   // j = k*B + b
  int v = (j < ntru[0]) ? inv[j] : -1;
  invT[(j & 63) * T_LEN + (j >> 6)] = v;
}

// ------------------------------------------- gi = X @ W_ih^T + b_ih (f16 MFMA)
__global__ __launch_bounds__(256) void k_gemm(const f16* __restrict__ X,
                                              const f16* __restrict__ W,
                                              const float* __restrict__ bias,
                                              f16* __restrict__ GI) {
  const int lane = threadIdx.x & 63;
  const int wave = threadIdx.x >> 6;
  const int m0 = blockIdx.x * 64 + wave * 16;
  const int n0 = blockIdx.y * 64;
  const int idx16 = lane & 15;
  const int kofs  = (lane >> 4) * 8;

  __shared__ __align__(16) f16 st[4][16][72];

  const f16* ap  = X + (size_t)(m0 + idx16) * H_INP + kofs;
  const f16* bp0 = W + (size_t)(n0 + idx16) * H_INP + kofs;

  f32x4 acc[4] = { {0,0,0,0}, {0,0,0,0}, {0,0,0,0}, {0,0,0,0} };
#pragma unroll
  for (int kt = 0; kt < 8; ++kt) {
    f16x8 a = *(const f16x8*)(ap + kt * 32);
#pragma unroll
    for (int nt = 0; nt < 4; ++nt) {
      f16x8 bb = *(const f16x8*)(bp0 + (size_t)nt * 16 * H_INP + kt * 32);
      acc[nt] = __builtin_amdgcn_mfma_f32_16x16x32_f16(a, bb, acc[nt], 0, 0, 0);
    }
  }
  // C/D layout: row = (lane>>4)*4 + r, col = lane&15
#pragma unroll
  for (int nt = 0; nt < 4; ++nt) {
    const int col = nt * 16 + idx16;
    const float bv = bias[n0 + col];
#pragma unroll
    for (int r = 0; r < 4; ++r)
      st[wave][(lane >> 4) * 4 + r][col] = (f16)(acc[nt][r] + bv);
  }
  // same-wave LDS RAW (compiler inserts lgkmcnt wait); no barrier needed
  {
    const int row = lane >> 2, seg = lane & 3;
    const uint4* sp = (const uint4*)&st[wave][row][seg * 16];
    uint4 v0 = sp[0], v1 = sp[1];
    uint4* gp = (uint4*)(GI + (size_t)(m0 + row) * G3 + n0 + seg * 16);
    gp[0] = v0; gp[1] = v1;
  }
}

// -------------------------------------------------- GRU scan, 1 column / block
// MFMA matvec, 8 waves. Wave w owns n-tiles {w+8i, i=0..5}: 48 f16x8 weight
// frags = 192 dwords/lane, which FITS the 256-reg combined V+A budget at
// waves_per_eu(2,2) (round 1's 4-wave/384-dword variant scratch-spilled:
// VGPR_Count=240 vs ~470 needed -> ~235 KB/CU/step of L2 scratch reloads).
// gfx950 MFMA reads A straight from AGPR (AV class) -> weights live in the
// AGPR half, no per-use moves. B = h replicated into 16 cols (C cols
// identical -> no cross-lane reduce). Mod-8 tile interleave keeps gate j's
// (r,z,n) rows (j, j+256, j+512) inside the producing wave -> ghs needs only
// intra-wave lgkmcnt ordering. hf/outb double-buffered -> ONE barrier/step.
// 2 waves/SIMD co-schedule: one wave's ds_read/gate latency hides under the
// other's 48-MFMA issue block.
__global__ __launch_bounds__(512)
__attribute__((amdgpu_waves_per_eu(2, 2)))
void k_scan(const f16* __restrict__ Whh,
            const f16* __restrict__ GI,
            const float* __restrict__ h0,
            const float* __restrict__ bhh,
            const unsigned short* __restrict__ tidx,
            const int* __restrict__ lens,
            const int* __restrict__ invT,
            float* __restrict__ out) {
  const int b = blockIdx.x;
  const int tid = threadIdx.x;
  const int w = tid >> 6;          // wave 0..7
  const int lane = tid & 63;
  const int g = lane >> 4;         // C-row group / k-group, 0..3
  const int c = lane & 15;         // replicated column / A-row
  const int hi = g & 1;            // gate tile-set selector for lanes<32

  __shared__ __align__(16) f16   GIbuf[2][SCH * G3];    // 24576 B
  __shared__ __align__(16) float outb[2][SCH * H_HID];  // 16384 B
  __shared__ __align__(16) float ghs[G3];               //  3072 B
  __shared__ __align__(16) f16   hf[2][H_HID];          //  1024 B
  __shared__ unsigned short tcol[T_LEN];                //  4096 B
  __shared__ int      invcol[T_LEN];                    //  8192 B

  const int L = lens[b];

  // ---- weights: wave w owns n-tiles t = w+8i (i=0..5), 8 k-frags each ----
  // A-frag layout (16x16x32): lane holds A[row = c][k = g*8 + e], e=0..7
  f16x8 wA[48];
#pragma unroll
  for (int i = 0; i < 6; ++i) {
    const f16* wp = Whh + (size_t)((w + 8 * i) * 16 + c) * H_HID + g * 8;
#pragma unroll
    for (int kt = 0; kt < 8; ++kt)
      wA[i * 8 + kt] = *(const f16x8*)(wp + kt * 32);
  }

  // gate element owned by lanes<32 of wave w: j covers tiles w and w+8,
  // whose r/z/n rows (j, j+256, j+512) are all produced by THIS wave.
  const int j = (w + 8 * hi) * 16 + c;
  const float bh0 = bhh[j];
  const float bh1 = bhh[H_HID + j];
  const float bh2 = bhh[2 * H_HID + j];

  // ---- stage per-column metadata + h0 ----
  for (int i = tid; i < T_LEN; i += 512) {
    tcol[i] = tidx[b * T_LEN + i];
    invcol[i] = invT[b * T_LEN + i];
  }
  float h_reg = 0.f;
  if (lane < 32) h_reg = h0[b * H_HID + j];
  if (tid < H_HID) hf[0][tid] = (f16)h0[b * H_HID + tid];
  __syncthreads();   // tcol/invcol/hf[0] ready

  const char* GIc = (const char*)GI;
  const int wavbase = w << 10;

  // issue async prefetch of chunk m into GIbuf[m&1] (16 B/lane DMA)
  auto issue_chunk = [&](int m) {
    {
      int p = tid << 4;                     // bytes [0, 8192)
      int r = p / 1536;
      int kk = m * SCH + r;
      int t = tcol[kk < L ? kk : 0] & (T_LEN - 1);
      const char* src = GIc + ((size_t)((t << 6) + b)) * 1536 + (p - r * 1536);
      char* dbase = (char*)GIbuf[m & 1] + wavbase;
      gldl16(src, dbase, (char*)GIbuf[m & 1] + p);
    }
    if (tid < 256) {                        // bytes [8192, 12288)
      int p = 8192 + (tid << 4);
      int r = p / 1536;
      int kk = m * SCH + r;
      int t = tcol[kk < L ? kk : 0] & (T_LEN - 1);
      const char* src = GIc + ((size_t)((t << 6) + b)) * 1536 + (p - r * 1536);
      char* dbase = (char*)GIbuf[m & 1] + 8192 + wavbase;
      gldl16(src, dbase, (char*)GIbuf[m & 1] + p);
    }
  };

  issue_chunk(0);
  __syncthreads();   // vmcnt(0) drain at barrier -> chunk 0 landed

  const f32x4 z4 = {0.f, 0.f, 0.f, 0.f};

  const int nchunks = (L + SCH - 1) >> 3;
  for (int n = 0; n < nchunks; ++n) {
    const int par = n & 1;
    if (n + 1 < nchunks) issue_chunk(n + 1);   // lands during this chunk
    // flush chunk n-1 output rows from outb[par^1] (other buffer: no race)
    if (n > 0) {
      int r = tid >> 6, c4 = (tid & 63) << 2;
      int kk = (n - 1) * SCH + r;
      if (kk < L) {
        int iv = invcol[kk];
        if (iv >= 0)
          *(float4*)(out + (size_t)iv * H_HID + c4) =
              *(const float4*)(outb[par ^ 1] + r * H_HID + c4);
      }
    }

    const int kbase = n * SCH;
    const int smax = (L - kbase < SCH) ? (L - kbase) : SCH;
    for (int s = 0; s < smax; ++s) {
      const int rd = (kbase + s) & 1;   // hf read buffer this step
      // --- B fragments streamed 2-deep from hf[rd] (broadcast b128 reads) ---
      const f16* hb = hf[rd] + g * 8;
      f16x8 b_cur = *(const f16x8*)(hb);
      f16x8 b_nxt = *(const f16x8*)(hb + 32);
      f32x4 acc[6];
#pragma unroll
      for (int i = 0; i < 6; ++i)
        acc[i] = __builtin_amdgcn_mfma_f32_16x16x32_f16(wA[i * 8], b_cur, z4, 0, 0, 0);
#pragma unroll
      for (int kt = 1; kt < 8; ++kt) {
        b_cur = b_nxt;
        if (kt < 7) b_nxt = *(const f16x8*)(hb + (kt + 1) * 32);
#pragma unroll
        for (int i = 0; i < 6; ++i)
          acc[i] = __builtin_amdgcn_mfma_f32_16x16x32_f16(wA[i * 8 + kt], b_cur, acc[i], 0, 0, 0);
      }
      // C replicated across cols; lane c==0 of each g-group writes 4 rows/tile
      if (c == 0) {
#pragma unroll
        for (int i = 0; i < 6; ++i)
          *(f32x4*)(&ghs[(w + 8 * i) * 16 + g * 4]) = acc[i];
      }
      // --- gates: intra-wave LDS RAW on ghs (lgkmcnt), no barrier ---
      if (lane < 32) {
        const f16* gib = GIbuf[par] + s * G3;
        const float gi0 = (float)gib[j];
        const float gi1 = (float)gib[H_HID + j];
        const float gi2 = (float)gib[2 * H_HID + j];
        const float ghr = ghs[j] + bh0;
        const float ghz = ghs[H_HID + j] + bh1;
        const float ghn = ghs[2 * H_HID + j] + bh2;
        const float rg = __builtin_amdgcn_rcpf(1.f + __expf(-(gi0 + ghr)));
        const float zg = __builtin_amdgcn_rcpf(1.f + __expf(-(gi1 + ghz)));
        const float xx = gi2 + rg * ghn;
        const float ng = 1.f - 2.f * __builtin_amdgcn_rcpf(1.f + __expf(2.f * xx));
        const float hn = (1.f - zg) * ng + zg * h_reg;
        h_reg = hn;
        hf[rd ^ 1][j] = (f16)hn;        // double-buffered: no read/write race
        outb[par][s * H_HID + j] = hn;
      }
      __syncthreads();   // hf[rd^1] complete before next step's bf reads
    }
  }
  // tail flush (last chunk)
  if (L > 0) {
    const int nc = nchunks - 1;
    int r = tid >> 6, c4 = (tid & 63) << 2;
    int kk = nc * SCH + r;
    if (kk < L) {
      int iv = invcol[kk];
      if (iv >= 0)
        *(float4*)(out + (size_t)iv * H_HID + c4) =
            *(const float4*)(outb[nc & 1] + r * H_HID + c4);
    }
  }
  if (lane < 32)
    out[(size_t)M_ROWS * H_HID + (size_t)b * H_HID + j] = h_reg;
}

// ---------------------------------------------------------------------------
extern "C" void kernel_launch(void* const* d_in, const int* in_sizes, int n_in,
                              void* d_out, int out_size, void* d_ws, size_t ws_size,
                              hipStream_t stream) {
  const float* x    = (const float*)d_in[0];
  const float* h0   = (const float*)d_in[1];
  const int*   mask = (const int*)d_in[2];
  const float* wih  = (const float*)d_in[3];
  const float* whh  = (const float*)d_in[4];
  const float* bih  = (const float*)d_in[5];
  const float* bhh  = (const float*)d_in[6];
  float* out = (float*)d_out;

  // workspace layout (~270.3 MB; invT reuses the X16 region after k_gemm)
  char* ws = (char*)d_ws;
  f16* X16   = (f16*)(ws + 0);                       //  67,108,864 B
  int* invT  = (int*)(ws + 0);                       //     524,288 B (after gemm)
  f16* Wih16 = (f16*)(ws + 67108864);                //     393,216 B
  f16* Whh16 = (f16*)(ws + 67502080);                //     393,216 B
  f16* GI    = (f16*)(ws + 67895296);                // 201,326,592 B
  unsigned short* tidx = (unsigned short*)(ws + 269221888);  // 262,144 B
  int* rowcnt  = (int*)(ws + 269484032);             //       8,192 B
  int* rowpref = (int*)(ws + 269492224);             //       8,192 B
  int* inv   = (int*)(ws + 269746176);               //     524,288 B
  int* lens  = (int*)(ws + 270270464);               //         256 B
  int* ntru  = (int*)(ws + 270270720);               //           4 B

  hipLaunchKernelGGL(k_zero, dim3(4096), dim3(256), 0, stream,
                     (float4*)d_out, out_size / 4);
  hipLaunchKernelGGL(k_cvt, dim3(4096), dim3(256), 0, stream,
                     (const float2*)x, (f16x2*)X16, M_ROWS * H_INP / 2);
  hipLaunchKernelGGL(k_cvt, dim3(96), dim3(256), 0, stream,
                     (const float2*)wih, (f16x2*)Wih16, G3 * H_INP / 2);
  hipLaunchKernelGGL(k_cvt, dim3(96), dim3(256), 0, stream,
                     (const float2*)whh, (f16x2*)Whh16, G3 * H_INP / 2);
  hipLaunchKernelGGL(k_prep_col, dim3(B_N), dim3(64), 0, stream,
                     mask, tidx, lens);
  hipLaunchKernelGGL(k_rowcnt, dim3(512), dim3(256), 0, stream, mask, rowcnt);
  hipLaunchKernelGGL(k_rowpref, dim3(1), dim3(512), 0, stream,
                     rowcnt, rowpref, ntru);
  hipLaunchKernelGGL(k_inv, dim3(512), dim3(256), 0, stream,
                     mask, rowpref, inv);
  hipLaunchKernelGGL(k_gemm, dim3(M_ROWS / 64, G3 / 64), dim3(256), 0, stream,
                     X16, Wih16, bih, GI);
  hipLaunchKernelGGL(k_invT, dim3(512), dim3(256), 0, stream,
                     inv, ntru, invT);
  hipLaunchKernelGGL(k_scan, dim3(B_N), dim3(512), 0, stream,
                     Whh16, GI, h0, bhh, tidx, lens, invT, out);
}